// Round 4
// baseline (335.785 us; speedup 1.0000x reference)
//
#include <hip/hip_runtime.h>
#include <math.h>

#define DD 1024
#define HH 2048
#define NBLK 256

typedef float f32x4 __attribute__((ext_vector_type(4)));
typedef short short8 __attribute__((ext_vector_type(8)));

__device__ __forceinline__ float b2f(unsigned short u) {
    return __uint_as_float(((unsigned int)u) << 16);
}
__device__ __forceinline__ unsigned short f2b(float f) {
    unsigned int x = __float_as_uint(f);
    unsigned int r = (x + 0x7FFFu + ((x >> 16) & 1u)) >> 16;
    return (unsigned short)r;
}

// ---------------- f32 -> bf16 straight copy ----------------
__global__ __launch_bounds__(256) void k_f2b(const float* __restrict__ in,
                                             unsigned short* __restrict__ out, int n) {
    int i = (blockIdx.x * 256 + threadIdx.x) * 4;
    if (i < n) {
        float4 v = *(const float4*)(in + i);
        ushort4 o;
        o.x = f2b(v.x); o.y = f2b(v.y); o.z = f2b(v.z); o.w = f2b(v.w);
        *(ushort4*)(out + i) = o;
    }
}

// ---------------- f32 [R][C] -> bf16 [C][R] transpose ----------------
__global__ __launch_bounds__(256) void k_tr(const float* __restrict__ in,
                                            unsigned short* __restrict__ out,
                                            int R, int C) {
    __shared__ float tile[64][65];
    const int c0 = blockIdx.x * 64;
    const int r0 = blockIdx.y * 64;
    const int t = threadIdx.x;
    const int cc = t & 63, rb = t >> 6;
    #pragma unroll
    for (int p = 0; p < 16; ++p) {
        int rr = p * 4 + rb;
        tile[rr][cc] = in[(size_t)(r0 + rr) * C + c0 + cc];
    }
    __syncthreads();
    #pragma unroll
    for (int p = 0; p < 16; ++p) {
        int rr = p * 4 + rb;
        out[(size_t)(c0 + rr) * R + r0 + cc] = f2b(tile[cc][rr]);
    }
}

// ---------------- P = (W1^T @ W3^T) .* W2, bf16 MFMA ----------------
__global__ __launch_bounds__(256) void k_gemmP(const unsigned short* __restrict__ W1T,
                                               const unsigned short* __restrict__ W3b,
                                               const float* __restrict__ W2,
                                               unsigned short* __restrict__ Pb) {
    __shared__ unsigned short At[128][40];
    __shared__ unsigned short Bt[128][40];
    const int m0 = blockIdx.y * 128;
    const int k0 = blockIdx.x * 128;
    const int t = threadIdx.x;
    const int r = t & 127, half = t >> 7;
    const int wv = t >> 6, l = t & 63;
    const int wr = wv >> 1, wc = wv & 1;
    const int fr = l & 15, fg = l >> 4;

    f32x4 acc[4][4] = {};
    for (int i0 = 0; i0 < DD; i0 += 32) {
        {
            const float4* sa = (const float4*)(W1T + (size_t)(m0 + r) * DD + i0 + half * 16);
            const float4* sb = (const float4*)(W3b + (size_t)(k0 + r) * DD + i0 + half * 16);
            float4 a0 = sa[0], a1 = sa[1];
            float4 b0 = sb[0], b1 = sb[1];
            float4* da = (float4*)&At[r][half * 16];
            float4* db = (float4*)&Bt[r][half * 16];
            da[0] = a0; da[1] = a1;
            db[0] = b0; db[1] = b1;
        }
        __syncthreads();
        short8 af[4], bf[4];
        #pragma unroll
        for (int a = 0; a < 4; ++a)
            af[a] = *(const short8*)&At[wr * 64 + a * 16 + fr][fg * 8];
        #pragma unroll
        for (int b = 0; b < 4; ++b)
            bf[b] = *(const short8*)&Bt[wc * 64 + b * 16 + fr][fg * 8];
        #pragma unroll
        for (int a = 0; a < 4; ++a)
            #pragma unroll
            for (int b = 0; b < 4; ++b)
                acc[a][b] = __builtin_amdgcn_mfma_f32_16x16x32_bf16(af[a], bf[b], acc[a][b], 0, 0, 0);
        __syncthreads();
    }
    #pragma unroll
    for (int a = 0; a < 4; ++a) {
        #pragma unroll
        for (int b = 0; b < 4; ++b) {
            #pragma unroll
            for (int j = 0; j < 4; ++j) {
                int row = m0 + wr * 64 + a * 16 + fg * 4 + j;
                int col = k0 + wc * 64 + b * 16 + fr;
                size_t idx = (size_t)row * HH + col;
                Pb[idx] = f2b(acc[a][b][j] * W2[idx]);
            }
        }
    }
}

// ---------------- init: logq0 + barrier zero ----------------
__global__ __launch_bounds__(1024) void k_init(const float* __restrict__ x0,
                                               float* __restrict__ logq,
                                               unsigned* __restrict__ bar) {
    int t = threadIdx.x;
    if (t < 64) bar[t] = 0u;
    float xv = x0[t];
    float s = xv * xv;
    #pragma unroll
    for (int o = 1; o < 64; o <<= 1) s += __shfl_xor(s, o, 64);
    __shared__ float red[16];
    if ((t & 63) == 0) red[t >> 6] = s;
    __syncthreads();
    if (t == 0) {
        float r = 0.f;
        #pragma unroll
        for (int q = 0; q < 16; ++q) r += red[q];
        logq[0] = -0.5f * r - 0.5f * 1024.0f * 1.8378770664093453f;
    }
}

// ---------------- grid barrier: device-scope RMWs (memory-side, XCD-safe) ----------------
__device__ __forceinline__ void gbar(unsigned* cnt, unsigned* gen, unsigned g) {
    __syncthreads();
    if (threadIdx.x == 0) {
        __threadfence();                       // flush this block's data writes
        unsigned a = atomicAdd(cnt, 1u);       // device-scope RMW
        if (a == NBLK * g - 1) {
            atomicExch(gen, g);                // release: RMW store
        } else {
            while (atomicOr(gen, 0u) < g)      // RMW read: never cache-stale
                __builtin_amdgcn_s_sleep(4);
        }
        __threadfence();                       // order subsequent data reads
    }
    __syncthreads();
}

// ---------------- persistent RK4 chain ----------------
__global__ __launch_bounds__(256) void k_chain(
    const unsigned short* __restrict__ W1T,  // [2048][1024]
    const unsigned short* __restrict__ W2T,  // [2048][2048]
    const unsigned short* __restrict__ W3T,  // [1024][2048]
    const unsigned short* __restrict__ Pb,   // [2048][2048]
    const float* __restrict__ x0,
    const float* __restrict__ b1, const float* __restrict__ wt,
    const float* __restrict__ b2, const float* __restrict__ b3,
    float* __restrict__ xs_g, float* __restrict__ h1_g, float* __restrict__ h2_g,
    float* __restrict__ divpart, const float* __restrict__ logq0_p,
    float* __restrict__ out, unsigned* __restrict__ bar) {
    __shared__ float vec[2048];
    __shared__ float wred[4];
    const int t = threadIdx.x, b = blockIdx.x;
    const int wib = t >> 6, lane = t & 63;
    const int gw = (b << 2) + wib;          // 0..1023
    const int j = gw;                        // owned x index
    unsigned* cnt = bar;
    unsigned* gen = bar + 32;
    unsigned g = 0;

    float x_j = x0[j];
    float xacc_j = x_j;
    float logq_r = (b == 0 && wib == 0) ? logq0_p[0] : 0.f;
    const float bt3 = b3[j];

    for (int s = 0; s < 8; ++s) {
        const int ss = s & 3;
        const float tcur = (s >> 2) * 0.5f + ((ss == 0) ? 0.f : (ss == 3) ? 0.5f : 0.25f);
        const float cacc = (ss == 1 || ss == 2) ? (1.f / 6.f) : (1.f / 12.f);

        // ---- Phase A: h1 = tanh(W1T·xs + b1 + t·wt); u kept in regs ----
        {
            const float* src = (s == 0) ? x0 : xs_g;
            for (int i = t; i < 1024; i += 256) vec[i] = src[i];
        }
        if (b == 0 && wib == 0 && s > 0) {
            int sp = (s - 1) & 3;
            float cprev = (sp == 1 || sp == 2) ? (1.f / 6.f) : (1.f / 12.f);
            float d = 0.f;
            #pragma unroll
            for (int q = 0; q < 4; ++q) d += divpart[lane + (q << 6)];
            #pragma unroll
            for (int o = 1; o < 64; o <<= 1) d += __shfl_xor(d, o, 64);
            logq_r -= cprev * d;
        }
        __syncthreads();
        float u0, u1;
        {
            float acc0 = 0.f, acc1 = 0.f;
            const unsigned short* Wr0 = W1T + (size_t)(2 * gw) * DD;
            const unsigned short* Wr1 = Wr0 + DD;
            #pragma unroll
            for (int rep = 0; rep < 2; ++rep) {
                int idx = rep * 512 + lane * 8;
                short8 a0 = *(const short8*)(Wr0 + idx);
                short8 a1 = *(const short8*)(Wr1 + idx);
                #pragma unroll
                for (int e = 0; e < 8; ++e) {
                    float xv = vec[idx + e];
                    acc0 += b2f((unsigned short)a0[e]) * xv;
                    acc1 += b2f((unsigned short)a1[e]) * xv;
                }
            }
            #pragma unroll
            for (int o = 1; o < 64; o <<= 1) {
                acc0 += __shfl_xor(acc0, o, 64);
                acc1 += __shfl_xor(acc1, o, 64);
            }
            int m0 = 2 * gw, m1 = m0 + 1;
            float h0 = tanhf(b1[m0] + tcur * wt[m0] + acc0);
            float h1 = tanhf(b1[m1] + tcur * wt[m1] + acc1);
            u0 = 1.f - h0 * h0; u1 = 1.f - h1 * h1;
            if (lane == 0) { h1_g[m0] = h0; h1_g[m1] = h1; }
        }
        gbar(cnt, gen, ++g);

        // ---- Phase B: h2 = tanh(W2T·h1 + b2) ----
        for (int i = t; i < 2048; i += 256) vec[i] = h1_g[i];
        __syncthreads();
        {
            float acc0 = 0.f, acc1 = 0.f;
            const unsigned short* Wr0 = W2T + (size_t)(2 * gw) * HH;
            const unsigned short* Wr1 = Wr0 + HH;
            #pragma unroll
            for (int rep = 0; rep < 4; ++rep) {
                int idx = rep * 512 + lane * 8;
                short8 a0 = *(const short8*)(Wr0 + idx);
                short8 a1 = *(const short8*)(Wr1 + idx);
                #pragma unroll
                for (int e = 0; e < 8; ++e) {
                    float hv = vec[idx + e];
                    acc0 += b2f((unsigned short)a0[e]) * hv;
                    acc1 += b2f((unsigned short)a1[e]) * hv;
                }
            }
            #pragma unroll
            for (int o = 1; o < 64; o <<= 1) {
                acc0 += __shfl_xor(acc0, o, 64);
                acc1 += __shfl_xor(acc1, o, 64);
            }
            int k0 = 2 * gw, k1 = k0 + 1;
            float q0 = tanhf(b2[k0] + acc0);
            float q1 = tanhf(b2[k1] + acc1);
            if (lane == 0) { h2_g[k0] = q0; h2_g[k1] = q1; }
        }
        gbar(cnt, gen, ++g);

        // ---- Phase C: v = W3T·h2 + b3; div partials; state update ----
        for (int i = t; i < 2048; i += 256) vec[i] = h2_g[i];
        __syncthreads();
        {
            float accv = 0.f, accd0 = 0.f, accd1 = 0.f;
            const unsigned short* Wr = W3T + (size_t)j * HH;
            const unsigned short* Pr0 = Pb + (size_t)(2 * gw) * HH;
            const unsigned short* Pr1 = Pr0 + HH;
            #pragma unroll
            for (int rep = 0; rep < 4; ++rep) {
                int idx = rep * 512 + lane * 8;
                short8 wv = *(const short8*)(Wr + idx);
                short8 p0 = *(const short8*)(Pr0 + idx);
                short8 p1 = *(const short8*)(Pr1 + idx);
                #pragma unroll
                for (int e = 0; e < 8; ++e) {
                    float hv = vec[idx + e];
                    float wk = 1.f - hv * hv;
                    accv  += b2f((unsigned short)wv[e]) * hv;
                    accd0 += b2f((unsigned short)p0[e]) * wk;
                    accd1 += b2f((unsigned short)p1[e]) * wk;
                }
            }
            #pragma unroll
            for (int o = 1; o < 64; o <<= 1) {
                accv  += __shfl_xor(accv, o, 64);
                accd0 += __shfl_xor(accd0, o, 64);
                accd1 += __shfl_xor(accd1, o, 64);
            }
            float vj = accv + bt3;
            xacc_j += cacc * vj;                 // (dt/6)*c_s*v
            float xs_j;
            if (ss < 3) xs_j = x_j + ((ss == 2) ? 0.5f : 0.25f) * vj;
            else { x_j = xacc_j; xs_j = x_j; }   // step boundary
            if (lane == 0) {
                if (s == 7) out[j] = x_j;
                else xs_g[j] = xs_j;
            }
            float dsum = u0 * accd0 + u1 * accd1;
            if (lane == 0) wred[wib] = dsum;
        }
        __syncthreads();
        if (t == 0) divpart[b] = wred[0] + wred[1] + wred[2] + wred[3];
        gbar(cnt, gen, ++g);
    }

    // final logq (stage 7 divergence)
    if (b == 0 && wib == 0) {
        float d = 0.f;
        #pragma unroll
        for (int q = 0; q < 4; ++q) d += divpart[lane + (q << 6)];
        #pragma unroll
        for (int o = 1; o < 64; o <<= 1) d += __shfl_xor(d, o, 64);
        logq_r -= (1.f / 12.f) * d;
        if (lane == 0) out[DD] = logq_r;
    }
}

extern "C" void kernel_launch(void* const* d_in, const int* in_sizes, int n_in,
                              void* d_out, int out_size, void* d_ws, size_t ws_size,
                              hipStream_t stream) {
    const float* x0 = (const float*)d_in[0];
    const float* W1 = (const float*)d_in[1];
    const float* b1 = (const float*)d_in[2];
    const float* wt = (const float*)d_in[3];
    const float* W2 = (const float*)d_in[4];
    const float* b2 = (const float*)d_in[5];
    const float* W3 = (const float*)d_in[6];
    const float* b3 = (const float*)d_in[7];
    float* out = (float*)d_out;

    char* ws = (char*)d_ws;
    const size_t MB = 1024 * 1024;
    unsigned short* Pb  = (unsigned short*)(ws);            // 8 MB
    unsigned short* W1T = (unsigned short*)(ws + 8 * MB);   // 4 MB
    unsigned short* W3b = (unsigned short*)(ws + 12 * MB);  // 4 MB
    unsigned short* W2T = (unsigned short*)(ws + 16 * MB);  // 8 MB
    unsigned short* W3T = (unsigned short*)(ws + 24 * MB);  // 4 MB
    float* fb = (float*)(ws + 28 * MB);
    float* xs_g    = fb;                // 1024
    float* h1_g    = fb + 1024;         // 2048
    float* h2_g    = fb + 3072;         // 2048
    float* divpart = fb + 5120;         // 256
    float* logq    = fb + 5376;         // 1
    unsigned* bar  = (unsigned*)(fb + 5440);  // 64 uints

    // ---- precompute ----
    k_f2b<<<(HH * DD) / 1024, 256, 0, stream>>>(W3, W3b, HH * DD);
    k_tr<<<dim3(32, 16), 256, 0, stream>>>(W1, W1T, DD, HH);   // -> [2048][1024]
    k_tr<<<dim3(32, 32), 256, 0, stream>>>(W2, W2T, HH, HH);   // -> [2048][2048]
    k_tr<<<dim3(16, 32), 256, 0, stream>>>(W3, W3T, HH, DD);   // -> [1024][2048]
    k_gemmP<<<dim3(16, 16), 256, 0, stream>>>(W1T, W3b, W2, Pb);
    k_init<<<1, 1024, 0, stream>>>(x0, logq, bar);

    // ---- persistent chain: 256 blocks (1/CU), plain launch ----
    k_chain<<<NBLK, 256, 0, stream>>>(W1T, W2T, W3T, Pb, x0, b1, wt, b2, b3,
                                      xs_g, h1_g, h2_g, divpart, logq, out, bar);
}

// Round 5
// 223.048 us; speedup vs baseline: 1.5054x; 1.5054x over previous
//
#include <hip/hip_runtime.h>
#include <math.h>

#define DD 1024
#define HH 2048
#define NBLK 128

typedef float f32x4 __attribute__((ext_vector_type(4)));
typedef short short8 __attribute__((ext_vector_type(8)));

__device__ __forceinline__ float b2f(unsigned short u) {
    return __uint_as_float(((unsigned int)u) << 16);
}
__device__ __forceinline__ unsigned short f2b(float f) {
    unsigned int x = __float_as_uint(f);
    unsigned int r = (x + 0x7FFFu + ((x >> 16) & 1u)) >> 16;
    return (unsigned short)r;
}

// ---------------- merged precompute: W3->bf16, W1T, W2T, W3T ----------------
// blocks: [0,2048) f2b W3 | [2048,2560) trans W1 | [2560,3584) trans W2 | [3584,4096) trans W3
__global__ __launch_bounds__(256) void k_pre(const float* __restrict__ W1,
                                             const float* __restrict__ W2,
                                             const float* __restrict__ W3,
                                             unsigned short* __restrict__ W1T,
                                             unsigned short* __restrict__ W2T,
                                             unsigned short* __restrict__ W3T,
                                             unsigned short* __restrict__ W3b) {
    __shared__ float tile[64][65];
    const int b = blockIdx.x, t = threadIdx.x;
    if (b < 2048) {
        int i = (b * 256 + t) * 4;
        float4 v = *(const float4*)(W3 + i);
        ushort4 o;
        o.x = f2b(v.x); o.y = f2b(v.y); o.z = f2b(v.z); o.w = f2b(v.w);
        *(ushort4*)(W3b + i) = o;
        return;
    }
    const float* in; unsigned short* out; int R, C, bx, by;
    if (b < 2560)      { int bb = b - 2048; in = W1; out = W1T; R = DD; C = HH; bx = bb & 31; by = bb >> 5; }
    else if (b < 3584) { int bb = b - 2560; in = W2; out = W2T; R = HH; C = HH; bx = bb & 31; by = bb >> 5; }
    else               { int bb = b - 3584; in = W3; out = W3T; R = HH; C = DD; bx = bb & 15; by = bb >> 4; }
    const int c0 = bx * 64, r0 = by * 64;
    const int cc = t & 63, rb = t >> 6;
    #pragma unroll
    for (int p = 0; p < 16; ++p) {
        int rr = p * 4 + rb;
        tile[rr][cc] = in[(size_t)(r0 + rr) * C + c0 + cc];
    }
    __syncthreads();
    #pragma unroll
    for (int p = 0; p < 16; ++p) {
        int rr = p * 4 + rb;
        out[(size_t)(c0 + rr) * R + r0 + cc] = f2b(tile[cc][rr]);
    }
}

// ---------------- P = (W1^T @ W3^T) .* W2, bf16 MFMA (+ barrier zero) ----------------
__global__ __launch_bounds__(256) void k_gemmP(const unsigned short* __restrict__ W1T,
                                               const unsigned short* __restrict__ W3b,
                                               const float* __restrict__ W2,
                                               unsigned short* __restrict__ Pb,
                                               unsigned* __restrict__ bar) {
    const int t = threadIdx.x;
    if (blockIdx.x == 0 && blockIdx.y == 0 && t < 64) {
        #pragma unroll
        for (int q = 0; q < 9; ++q) bar[t + q * 64] = 0u;
    }
    __shared__ unsigned short At[128][40];
    __shared__ unsigned short Bt[128][40];
    const int m0 = blockIdx.y * 128;
    const int k0 = blockIdx.x * 128;
    const int r = t & 127, half = t >> 7;
    const int wv = t >> 6, l = t & 63;
    const int wr = wv >> 1, wc = wv & 1;
    const int fr = l & 15, fg = l >> 4;

    f32x4 acc[4][4] = {};
    for (int i0 = 0; i0 < DD; i0 += 32) {
        {
            const float4* sa = (const float4*)(W1T + (size_t)(m0 + r) * DD + i0 + half * 16);
            const float4* sb = (const float4*)(W3b + (size_t)(k0 + r) * DD + i0 + half * 16);
            float4 a0 = sa[0], a1 = sa[1];
            float4 b0 = sb[0], b1 = sb[1];
            float4* da = (float4*)&At[r][half * 16];
            float4* db = (float4*)&Bt[r][half * 16];
            da[0] = a0; da[1] = a1;
            db[0] = b0; db[1] = b1;
        }
        __syncthreads();
        short8 af[4], bf[4];
        #pragma unroll
        for (int a = 0; a < 4; ++a)
            af[a] = *(const short8*)&At[wr * 64 + a * 16 + fr][fg * 8];
        #pragma unroll
        for (int b = 0; b < 4; ++b)
            bf[b] = *(const short8*)&Bt[wc * 64 + b * 16 + fr][fg * 8];
        #pragma unroll
        for (int a = 0; a < 4; ++a)
            #pragma unroll
            for (int b = 0; b < 4; ++b)
                acc[a][b] = __builtin_amdgcn_mfma_f32_16x16x32_bf16(af[a], bf[b], acc[a][b], 0, 0, 0);
        __syncthreads();
    }
    #pragma unroll
    for (int a = 0; a < 4; ++a) {
        #pragma unroll
        for (int b = 0; b < 4; ++b) {
            #pragma unroll
            for (int j = 0; j < 4; ++j) {
                int row = m0 + wr * 64 + a * 16 + fg * 4 + j;
                int col = k0 + wc * 64 + b * 16 + fr;
                size_t idx = (size_t)row * HH + col;
                Pb[idx] = f2b(acc[a][b][j] * W2[idx]);
            }
        }
    }
}

// ---------------- tree grid barrier: 8 sectors x 16 blocks, device-scope RMWs ----------------
__device__ __forceinline__ void gbar(unsigned* bar, int b, unsigned g) {
    __syncthreads();
    if (threadIdx.x == 0) {
        const int sec = b >> 4;
        unsigned* scnt = bar + sec * 32;          // lines 0..7
        unsigned* rcnt = bar + 256;               // line 8
        unsigned* gen  = bar + 288;               // line 9
        unsigned* sgen = bar + 320 + sec * 32;    // lines 10..17
        __threadfence();
        unsigned a = atomicAdd(scnt, 1u);
        if (a == 16u * g - 1u) {
            unsigned r2 = atomicAdd(rcnt, 1u);
            if (r2 == 8u * g - 1u) atomicExch(gen, g);
            else while (atomicOr(gen, 0u) < g) __builtin_amdgcn_s_sleep(2);
            atomicExch(sgen, g);
        } else {
            while (atomicOr(sgen, 0u) < g) __builtin_amdgcn_s_sleep(2);
        }
        __threadfence();
    }
    __syncthreads();
}

// ---------------- persistent RK4 chain: 128 blocks, 4 waves each ----------------
__global__ __launch_bounds__(256) void k_chain(
    const unsigned short* __restrict__ W1T,  // [2048][1024]
    const unsigned short* __restrict__ W2T,  // [2048][2048]
    const unsigned short* __restrict__ W3T,  // [1024][2048]
    const unsigned short* __restrict__ Pb,   // [2048][2048]
    const float* __restrict__ x0,
    const float* __restrict__ b1, const float* __restrict__ wt,
    const float* __restrict__ b2, const float* __restrict__ b3,
    float* __restrict__ xs_g, float* __restrict__ h1_g, float* __restrict__ h2_g,
    float* __restrict__ divpart, float* __restrict__ out,
    unsigned* __restrict__ bar) {
    __shared__ float vec[2048];
    __shared__ float wred[4];
    const int t = threadIdx.x, b = blockIdx.x;
    const int wib = t >> 6, lane = t & 63;
    const int gw = (b << 2) + wib;            // 0..511
    const int m0 = gw * 4;                    // owned h-rows (4)
    const int j0 = gw * 2;                    // owned x-rows (2)
    unsigned g = 0;

    // hoisted per-wave constants
    const float bb1_0 = b1[m0], bb1_1 = b1[m0 + 1], bb1_2 = b1[m0 + 2], bb1_3 = b1[m0 + 3];
    const float wtv0 = wt[m0], wtv1 = wt[m0 + 1], wtv2 = wt[m0 + 2], wtv3 = wt[m0 + 3];
    const float bb2_0 = b2[m0], bb2_1 = b2[m0 + 1], bb2_2 = b2[m0 + 2], bb2_3 = b2[m0 + 3];
    const float bt3_0 = b3[j0], bt3_1 = b3[j0 + 1];

    float x_0 = x0[j0], x_1 = x0[j0 + 1];
    float xac0 = x_0, xac1 = x_1;

    float logq_r = 0.f;
    if (b == 0 && wib == 0) {
        float ssum = 0.f;
        #pragma unroll
        for (int q = 0; q < 16; ++q) { float xv = x0[lane + (q << 6)]; ssum += xv * xv; }
        #pragma unroll
        for (int o = 1; o < 64; o <<= 1) ssum += __shfl_xor(ssum, o, 64);
        logq_r = -0.5f * ssum - 0.5f * 1024.0f * 1.8378770664093453f;
    }

    for (int s = 0; s < 8; ++s) {
        const int ss = s & 3;
        const float tcur = (s >> 2) * 0.5f + ((ss == 0) ? 0.f : (ss == 3) ? 0.5f : 0.25f);
        const float cacc = (ss == 1 || ss == 2) ? (1.f / 6.f) : (1.f / 12.f);

        // ---- Phase A: h1 = tanh(W1T·xs + b1 + t·wt); u kept in regs ----
        ((float4*)vec)[t] = ((const float4*)((s == 0) ? x0 : xs_g))[t];
        if (b == 0 && wib == 0 && s > 0) {
            int sp = (s - 1) & 3;
            float cprev = (sp == 1 || sp == 2) ? (1.f / 6.f) : (1.f / 12.f);
            float d = divpart[lane] + divpart[lane + 64];
            #pragma unroll
            for (int o = 1; o < 64; o <<= 1) d += __shfl_xor(d, o, 64);
            logq_r -= cprev * d;
        }
        __syncthreads();
        float u0, u1, u2, u3;
        {
            float a0 = 0.f, a1 = 0.f, a2 = 0.f, a3 = 0.f;
            const unsigned short* Wr = W1T + (size_t)m0 * DD;
            #pragma unroll
            for (int rep = 0; rep < 2; ++rep) {
                int idx = rep * 512 + lane * 8;
                short8 r0 = *(const short8*)(Wr + idx);
                short8 r1 = *(const short8*)(Wr + DD + idx);
                short8 r2 = *(const short8*)(Wr + 2 * DD + idx);
                short8 r3 = *(const short8*)(Wr + 3 * DD + idx);
                #pragma unroll
                for (int e = 0; e < 8; ++e) {
                    float xv = vec[idx + e];
                    a0 += b2f((unsigned short)r0[e]) * xv;
                    a1 += b2f((unsigned short)r1[e]) * xv;
                    a2 += b2f((unsigned short)r2[e]) * xv;
                    a3 += b2f((unsigned short)r3[e]) * xv;
                }
            }
            #pragma unroll
            for (int o = 1; o < 64; o <<= 1) {
                a0 += __shfl_xor(a0, o, 64); a1 += __shfl_xor(a1, o, 64);
                a2 += __shfl_xor(a2, o, 64); a3 += __shfl_xor(a3, o, 64);
            }
            float h0 = tanhf(bb1_0 + tcur * wtv0 + a0);
            float h1 = tanhf(bb1_1 + tcur * wtv1 + a1);
            float h2 = tanhf(bb1_2 + tcur * wtv2 + a2);
            float h3 = tanhf(bb1_3 + tcur * wtv3 + a3);
            u0 = 1.f - h0 * h0; u1 = 1.f - h1 * h1; u2 = 1.f - h2 * h2; u3 = 1.f - h3 * h3;
            if (lane == 0) *(float4*)(h1_g + m0) = make_float4(h0, h1, h2, h3);
        }
        gbar(bar, b, ++g);

        // ---- Phase B: h2 = tanh(W2T·h1 + b2) ----
        ((float4*)vec)[t] = ((const float4*)h1_g)[t];
        ((float4*)vec)[t + 256] = ((const float4*)h1_g)[t + 256];
        __syncthreads();
        {
            float a0 = 0.f, a1 = 0.f, a2 = 0.f, a3 = 0.f;
            const unsigned short* Wr = W2T + (size_t)m0 * HH;
            #pragma unroll
            for (int rep = 0; rep < 4; ++rep) {
                int idx = rep * 512 + lane * 8;
                short8 r0 = *(const short8*)(Wr + idx);
                short8 r1 = *(const short8*)(Wr + HH + idx);
                short8 r2 = *(const short8*)(Wr + 2 * HH + idx);
                short8 r3 = *(const short8*)(Wr + 3 * HH + idx);
                #pragma unroll
                for (int e = 0; e < 8; ++e) {
                    float hv = vec[idx + e];
                    a0 += b2f((unsigned short)r0[e]) * hv;
                    a1 += b2f((unsigned short)r1[e]) * hv;
                    a2 += b2f((unsigned short)r2[e]) * hv;
                    a3 += b2f((unsigned short)r3[e]) * hv;
                }
            }
            #pragma unroll
            for (int o = 1; o < 64; o <<= 1) {
                a0 += __shfl_xor(a0, o, 64); a1 += __shfl_xor(a1, o, 64);
                a2 += __shfl_xor(a2, o, 64); a3 += __shfl_xor(a3, o, 64);
            }
            float q0 = tanhf(bb2_0 + a0);
            float q1 = tanhf(bb2_1 + a1);
            float q2 = tanhf(bb2_2 + a2);
            float q3 = tanhf(bb2_3 + a3);
            if (lane == 0) *(float4*)(h2_g + m0) = make_float4(q0, q1, q2, q3);
        }
        gbar(bar, b, ++g);

        // ---- Phase C: v = W3T·h2 + b3 (2 rows); div partials (4 P-rows); state ----
        ((float4*)vec)[t] = ((const float4*)h2_g)[t];
        ((float4*)vec)[t + 256] = ((const float4*)h2_g)[t + 256];
        __syncthreads();
        {
            float av0 = 0.f, av1 = 0.f, ad0 = 0.f, ad1 = 0.f, ad2 = 0.f, ad3 = 0.f;
            const unsigned short* Vr = W3T + (size_t)j0 * HH;
            const unsigned short* Pr = Pb + (size_t)m0 * HH;
            #pragma unroll
            for (int rep = 0; rep < 4; ++rep) {
                int idx = rep * 512 + lane * 8;
                short8 v0 = *(const short8*)(Vr + idx);
                short8 v1 = *(const short8*)(Vr + HH + idx);
                short8 p0 = *(const short8*)(Pr + idx);
                short8 p1 = *(const short8*)(Pr + HH + idx);
                short8 p2 = *(const short8*)(Pr + 2 * HH + idx);
                short8 p3 = *(const short8*)(Pr + 3 * HH + idx);
                #pragma unroll
                for (int e = 0; e < 8; ++e) {
                    float hv = vec[idx + e];
                    float wk = 1.f - hv * hv;
                    av0 += b2f((unsigned short)v0[e]) * hv;
                    av1 += b2f((unsigned short)v1[e]) * hv;
                    ad0 += b2f((unsigned short)p0[e]) * wk;
                    ad1 += b2f((unsigned short)p1[e]) * wk;
                    ad2 += b2f((unsigned short)p2[e]) * wk;
                    ad3 += b2f((unsigned short)p3[e]) * wk;
                }
            }
            #pragma unroll
            for (int o = 1; o < 64; o <<= 1) {
                av0 += __shfl_xor(av0, o, 64); av1 += __shfl_xor(av1, o, 64);
                ad0 += __shfl_xor(ad0, o, 64); ad1 += __shfl_xor(ad1, o, 64);
                ad2 += __shfl_xor(ad2, o, 64); ad3 += __shfl_xor(ad3, o, 64);
            }
            float vj0 = av0 + bt3_0, vj1 = av1 + bt3_1;
            xac0 += cacc * vj0; xac1 += cacc * vj1;
            float xs0, xs1;
            if (ss < 3) {
                float aco = (ss == 2) ? 0.5f : 0.25f;
                xs0 = x_0 + aco * vj0; xs1 = x_1 + aco * vj1;
            } else {
                x_0 = xac0; x_1 = xac1; xs0 = x_0; xs1 = x_1;
            }
            if (lane == 0) {
                if (s == 7) { out[j0] = x_0; out[j0 + 1] = x_1; }
                else { xs_g[j0] = xs0; xs_g[j0 + 1] = xs1; }
            }
            float dsum = u0 * ad0 + u1 * ad1 + u2 * ad2 + u3 * ad3;
            if (lane == 0) wred[wib] = dsum;
        }
        __syncthreads();
        if (t == 0) divpart[b] = wred[0] + wred[1] + wred[2] + wred[3];
        gbar(bar, b, ++g);
    }

    // final logq (stage 7 divergence)
    if (b == 0 && wib == 0) {
        float d = divpart[lane] + divpart[lane + 64];
        #pragma unroll
        for (int o = 1; o < 64; o <<= 1) d += __shfl_xor(d, o, 64);
        logq_r -= (1.f / 12.f) * d;
        if (lane == 0) out[DD] = logq_r;
    }
}

extern "C" void kernel_launch(void* const* d_in, const int* in_sizes, int n_in,
                              void* d_out, int out_size, void* d_ws, size_t ws_size,
                              hipStream_t stream) {
    const float* x0 = (const float*)d_in[0];
    const float* W1 = (const float*)d_in[1];
    const float* b1 = (const float*)d_in[2];
    const float* wt = (const float*)d_in[3];
    const float* W2 = (const float*)d_in[4];
    const float* b2 = (const float*)d_in[5];
    const float* W3 = (const float*)d_in[6];
    const float* b3 = (const float*)d_in[7];
    float* out = (float*)d_out;

    char* ws = (char*)d_ws;
    const size_t MB = 1024 * 1024;
    unsigned short* Pb  = (unsigned short*)(ws);            // 8 MB
    unsigned short* W1T = (unsigned short*)(ws + 8 * MB);   // 4 MB
    unsigned short* W3b = (unsigned short*)(ws + 12 * MB);  // 4 MB
    unsigned short* W2T = (unsigned short*)(ws + 16 * MB);  // 8 MB
    unsigned short* W3T = (unsigned short*)(ws + 24 * MB);  // 4 MB
    float* fb = (float*)(ws + 28 * MB);
    float* xs_g    = fb;                      // 1024
    float* h1_g    = fb + 1024;               // 2048
    float* h2_g    = fb + 3072;               // 2048
    float* divpart = fb + 5120;               // 128
    unsigned* bar  = (unsigned*)(fb + 5248);  // 576 uints

    k_pre<<<4096, 256, 0, stream>>>(W1, W2, W3, W1T, W2T, W3T, W3b);
    k_gemmP<<<dim3(16, 16), 256, 0, stream>>>(W1T, W3b, W2, Pb, bar);
    k_chain<<<NBLK, 256, 0, stream>>>(W1T, W2T, W3T, Pb, x0, b1, wt, b2, b3,
                                      xs_g, h1_g, h2_g, divpart, out, bar);
}